// Round 13
// baseline (72.865 us; speedup 1.0000x reference)
//
#include <hip/hip_runtime.h>

typedef _Float16 f16;
typedef _Float16 f16x2 __attribute__((ext_vector_type(2)));
typedef _Float16 f16x8 __attribute__((ext_vector_type(8)));
typedef float f32x16 __attribute__((ext_vector_type(16)));
typedef unsigned int u32;
typedef unsigned int u32x4 __attribute__((ext_vector_type(4)));

static __device__ __forceinline__ u32 pk2(float lo, float hi) {
  union { f16 h[2]; u32 u; } v;
  v.h[0] = (f16)lo; v.h[1] = (f16)hi;
  return v.u;
}

// ---- fused prep: blocks 0..2047: W[f,d,e]->fp16 retile (XCD-PINNED);
//      blocks 2048..2111: decayed prefix scan of x -> st (transposed).
// W layout: byte = d*32768 + (e>>5)*8192 + f*64 + ((e>>3)&3)*16 + (e&7)*2
// Pinning: block bid performs canonical block w's work, where the low-4-bit
// permutation makes w's d-octant (KLOG=3) or d-quarter (KLOG=2) equal to
// bid%8 (resp. bid%4) == the XCD that k_main will READ that slice on.
template <int KLOG>
__global__ void k_pre(const float* __restrict__ W, char* __restrict__ wt,
                      const float* __restrict__ x, float* __restrict__ st) {
  int bid = blockIdx.x;
  if (bid < 2048) {
    int w;
    if (KLOG == 3) w = (bid & ~15) | (((bid & 7) << 1) | ((bid >> 3) & 1));
    else           w = (bid & ~15) | (((bid & 3) << 2) | ((bid >> 2) & 3));
    int t = w * 256 + threadIdx.x;
    long i = (long)t * 4;                      // 2M W elements, 4/thread
    int f = (int)(i >> 14);
    int k = (int)(i & 16383);
    float4 w4 = *(const float4*)(W + i);
    int d = k >> 7, e = k & 127;
    long byo = (long)d * 32768 + (e >> 5) * 8192 + f * 64 + ((e >> 3) & 3) * 16 + (e & 7) * 2;
    u32* dst = (u32*)(wt + byo);
    dst[0] = pk2(w4.x, w4.y);
    dst[1] = pk2(w4.z, w4.w);
  } else {
    int tid = (bid - 2048) * 256 + threadIdx.x;   // 16384 threads
    int e  = tid & 127;
    int bc = tid >> 7;
    int b  = bc >> 5;
    int ch = bc & 31;
    int t0 = ch * 64;
    const float* xb = x + (long)b * 2048 * 128 + e;
    float* sb = st + (long)e * 8192 + b * 2048;
    const float inv = 1.0f / 1.2f;
    float c = 0.f;
    if (ch > 0) {
      const float* xp = xb + (long)(t0 - 64) * 128;
      #pragma unroll
      for (int t = 0; t < 64; ++t) c = (c + xp[t * 128]) * inv;
    }
    const float* xq = xb + (long)t0 * 128;
    float* sq = sb + t0;
    #pragma unroll
    for (int t = 0; t < 64; ++t) { sq[t] = c; c = (c + xq[t * 128]) * inv; }
  }
}

// ---- final reduce: out = sum over KS K-split partials ----------------------
template <int KS>
__global__ void k_red(const float4* __restrict__ part, float4* __restrict__ out) {
  int i = blockIdx.x * 256 + threadIdx.x;          // 262144 float4
  float4 s = part[i];
  #pragma unroll
  for (int q = 1; q < KS; ++q) {
    float4 p = part[i + (long)q * 262144];
    s.x += p.x; s.y += p.y; s.z += p.z; s.w += p.w;
  }
  out[i] = s;
}

// ---------------- main: part[kq][token,f] = sum_{d in kq} (x*s) W ----------
// KLOG=3: grid 256, kq = bid&7 == XCD -> each XCD reads ONE 512KB W octant,
// written locally by the pinned k_pre -> W reads are local-L2-dirty hits.
// Each block processes 2 token-tiles sequentially (re-reads octant from
// local L2). 8 waves = f-half(ng) x e-quadrant(ep). 32x32x16 f16 MFMA.
// KLOG=2: R12 fallback (ws too small for 8 partials): kq = bid&3, 1 tile.
template <int KLOG>
__global__ __launch_bounds__(512, 2) void k_main(
    const float* __restrict__ x, const float* __restrict__ st,
    const char* __restrict__ wt, float* __restrict__ part) {
  constexpr int KS   = 1 << KLOG;      // K-split
  constexpr int DS   = 128 >> KLOG;    // d's per block (32 or 16)
  constexpr int NIT4 = DS / 4;         // super-iterations
  constexpr int XP   = DS + 4;         // x_lds padded row (words)
  constexpr int TL   = (KLOG == 3) ? 2 : 1;   // token tiles per block

  __shared__ u32 x_lds[128 * XP];
  __shared__ float red[128 * 129];

  const int tid  = threadIdx.x;
  const int bid  = blockIdx.x;
  const int kq   = bid & (KS - 1);
  const int ub   = bid >> KLOG;
  const int wv   = tid >> 6;
  const int lane = tid & 63;
  const int ng   = wv & 1;           // f half
  const int ep   = wv >> 1;          // e quadrant
  const int l31  = lane & 31;
  const int hi   = lane >> 5;

  const char* wtq = wt + (long)(kq * DS) * 32768 + ep * 8192 + ng * 4096;
  const int lboff = l31 * 64 + hi * 16;

  #pragma unroll 1
  for (int tl = 0; tl < TL; ++tl) {
    const int tokenBase = (ub * TL + tl) * 128;
    __syncthreads();   // prior tile's red reads / x_lds reads complete

    // stage x tile as duplicated half2 (xv,xv): [128 tok][DS d], d = kq*DS+it
    {
      int row = tid >> 2, c0 = (tid & 3) * (DS / 4);
      const float* src = x + (long)(tokenBase + row) * 128 + kq * DS + c0;
      u32* dst = &x_lds[row * XP + c0];
      if constexpr (DS == 32) {
        float4 v0 = *(const float4*)src;
        float4 v1 = *(const float4*)(src + 4);
        dst[0] = pk2(v0.x, v0.x); dst[1] = pk2(v0.y, v0.y);
        dst[2] = pk2(v0.z, v0.z); dst[3] = pk2(v0.w, v0.w);
        dst[4] = pk2(v1.x, v1.x); dst[5] = pk2(v1.y, v1.y);
        dst[6] = pk2(v1.z, v1.z); dst[7] = pk2(v1.w, v1.w);
      } else {
        float4 v0 = *(const float4*)src;
        dst[0] = pk2(v0.x, v0.x); dst[1] = pk2(v0.y, v0.y);
        dst[2] = pk2(v0.z, v0.z); dst[3] = pk2(v0.w, v0.w);
      }
    }

    // s: lane needs s[token = m*32+l31][e = ep*32 + kk*16 + hi*8 + j] as
    // half2 pairs -> sreg[m][kk][jj], 32 VGPRs.
    u32 sreg[4][2][4];
    {
      #pragma unroll
      for (int m = 0; m < 4; ++m)
        #pragma unroll
        for (int kk = 0; kk < 2; ++kk)
          #pragma unroll
          for (int jj = 0; jj < 4; ++jj) {
            const float* qp = st + (long)(ep * 32 + kk * 16 + hi * 8 + 2 * jj) * 8192
                                + tokenBase + m * 32 + l31;
            sreg[m][kk][jj] = pk2(qp[0], qp[8192]);
          }
    }
    __syncthreads();   // x_lds ready

    f32x16 acc[4][2];
    #pragma unroll
    for (int m = 0; m < 4; ++m)
      #pragma unroll
      for (int n = 0; n < 2; ++n)
        #pragma unroll
        for (int q = 0; q < 16; ++q) acc[m][n][q] = 0.f;

#define BLOAD(BUF, IT)                                                       \
    {                                                                        \
      int itc = (IT) > DS - 1 ? DS - 1 : (IT);                               \
      const char* wn = wtq + (long)itc * 32768;                              \
      BUF[0][0] = *(const f16x8*)(wn + lboff);                               \
      BUF[0][1] = *(const f16x8*)(wn + 2048 + lboff);                        \
      BUF[1][0] = *(const f16x8*)(wn + 32 + lboff);                          \
      BUF[1][1] = *(const f16x8*)(wn + 2048 + 32 + lboff);                   \
    }
#define STEP(BUF, XB, J)                                                     \
    {                                                                        \
      _Pragma("unroll")                                                      \
      for (int kk = 0; kk < 2; ++kk) {                                       \
        _Pragma("unroll")                                                    \
        for (int m = 0; m < 4; ++m) {                                        \
          f16x2 xv2;                                                         \
          *(u32*)&xv2 = XB[m][J];                                            \
          union { u32 u[4]; f16x8 v; } au;                                   \
          _Pragma("unroll")                                                  \
          for (int jj = 0; jj < 4; ++jj) {                                   \
            f16x2 s2;                                                        \
            *(u32*)&s2 = sreg[m][kk][jj];                                    \
            f16x2 p = xv2 * s2;                                              \
            au.u[jj] = *(u32*)&p;                                            \
          }                                                                  \
          acc[m][0] = __builtin_amdgcn_mfma_f32_32x32x16_f16(                \
              au.v, BUF[kk][0], acc[m][0], 0, 0, 0);                         \
          acc[m][1] = __builtin_amdgcn_mfma_f32_32x32x16_f16(                \
              au.v, BUF[kk][1], acc[m][1], 0, 0, 0);                         \
        }                                                                    \
      }                                                                      \
    }

    f16x8 ba[2][2], bb[2][2];
    BLOAD(ba, 0);

    #pragma unroll 1
    for (int it4 = 0; it4 < NIT4; ++it4) {
      u32x4 xb[4];
      #pragma unroll
      for (int m = 0; m < 4; ++m)
        xb[m] = *(const u32x4*)&x_lds[(m * 32 + l31) * XP + it4 * 4];
      int it = it4 * 4;
      BLOAD(bb, it + 1); STEP(ba, xb, 0);
      BLOAD(ba, it + 2); STEP(bb, xb, 1);
      BLOAD(bb, it + 3); STEP(ba, xb, 2);
      BLOAD(ba, it + 4); STEP(bb, xb, 3);
    }
#undef STEP
#undef BLOAD

    // epilogue: reduce the 4 e-quadrant waves (per f-half) in LDS, then store
    __syncthreads();
    #pragma unroll
    for (int round = 0; round < 4; ++round) {
      if (ep == round) {
        #pragma unroll
        for (int m = 0; m < 4; ++m)
          #pragma unroll
          for (int n = 0; n < 2; ++n)
            #pragma unroll
            for (int reg = 0; reg < 16; ++reg) {
              // C/D: col=l31 (f), row=(reg&3)+8*(reg>>2)+4*hi (token)
              int token = m * 32 + (reg & 3) + 8 * (reg >> 2) + 4 * hi;
              int idx = token * 129 + ng * 64 + n * 32 + l31;
              if (round == 0) red[idx] = acc[m][n][reg];
              else            red[idx] += acc[m][n][reg];
            }
      }
      __syncthreads();
    }
    float* outp = part + (long)kq * 1048576 + (long)tokenBase * 128;
    #pragma unroll
    for (int j = 0; j < 32; ++j) {
      int row = (tid >> 7) + j * 4;
      int col = tid & 127;
      outp[row * 128 + col] = red[row * 129 + col];
    }
  }
}

extern "C" void kernel_launch(void* const* d_in, const int* in_sizes, int n_in,
                              void* d_out, int out_size, void* d_ws, size_t ws_size,
                              hipStream_t stream) {
  const float* x = (const float*)d_in[0];        // [4,2048,128] f32
  const float* W = (const float*)d_in[1];        // [128,128,128] f32
  float* out  = (float*)d_out;                   // [4,2048,128] f32
  float* st   = (float*)d_ws;                    // 4 MB: s transposed [e][token]
  char*  wt   = (char*)d_ws + (4 << 20);         // 4 MB: W fp16 retiled
  float* part = (float*)((char*)d_ws + (8 << 20)); // K-split partials

  size_t need8 = (size_t)(8 << 20) + (size_t)8 * (4 << 20);  // 40 MB
  if (ws_size >= need8) {
    k_pre<3><<<dim3(2112), dim3(256), 0, stream>>>(W, wt, x, st);
    k_main<3><<<dim3(256), dim3(512), 0, stream>>>(x, st, wt, part);
    k_red<8><<<dim3(1024), dim3(256), 0, stream>>>((const float4*)part, (float4*)out);
  } else {
    k_pre<2><<<dim3(2112), dim3(256), 0, stream>>>(W, wt, x, st);
    k_main<2><<<dim3(256), dim3(512), 0, stream>>>(x, st, wt, part);
    k_red<4><<<dim3(1024), dim3(256), 0, stream>>>((const float4*)part, (float4*)out);
  }
}